// Round 12
// baseline (77.407 us; speedup 1.0000x reference)
//
#include <hip/hip_runtime.h>
#include <hip/hip_bf16.h>

// LocalFeatureAggregation: B=2, N=32768, K=16, CIN=8, COUT=64
// MFMA version 8: REGISTER-DIET build targeting <=128 total unified VGPRs
// -> 4 waves/SIMD (the 512-reg file steps residency at 64/128/256).
// Changes vs v7: serial per-point chains (no pairing; TLP replaces ILP),
// b2f/b3f/pbf are transient per-use loads from L2-hot workspace (opaque
// index defeats LICM re-hoisting), LSE streams row-by-row (no x24[24]),
// LSE scales prefolded in pack kernel, single X2/X3 tiles, PL aliases X1,
// per-iter pool epilogue. LDS 8896 B -> 16+ blocks/CU. launch_bounds(64,4).
// Tripwire: WRITE_SIZE must stay 16384 KB (no scratch spill).
// Grid = 8192 blocks x 2 iters x 4 points.

typedef __attribute__((ext_vector_type(8))) short short8v;
typedef __attribute__((ext_vector_type(4))) float float4v;

#define BN_INV 0.9999950000374997f
#define NFRAG 22
#define NSCAL 20
#define NLSE  208   // w1(32) g1s(8) b1(8) w2(128) g2s(16) b2(16)

// cheap float->bf16, round-half-up (1-ulp-on-ties vs RNE; inputs finite)
__device__ __forceinline__ ushort f2bf(float f) {
    return (ushort)((__float_as_uint(f) + 0x8000u) >> 16);
}
// pack two: low half = bf16(a), high half = bf16(b)
__device__ __forceinline__ uint pk2(float a, float b) {
    return __builtin_amdgcn_perm(__float_as_uint(b) + 0x8000u,
                                 __float_as_uint(a) + 0x8000u, 0x07060302u);
}
__device__ __forceinline__ ushort f2bf_rne(float f) {
    __hip_bfloat16 h = __float2bfloat16(f);
    return __builtin_bit_cast(ushort, h);
}

// ---- setup: pack per-lane MFMA B-fragments + scale/shift + LSE weights ----
// layout: [NFRAG][64] x 16B fragments, then [NSCAL][64] f32, then NLSE f32.
// frag order: 0 b1f0, 1 b1f1, 2-5 b2f[t], 6-13 b3f[2t+h], 14-21 pbf[2t+h].
__global__ __launch_bounds__(256)
void lfa_pack(const float* __restrict__ wm1, const float* __restrict__ wm2,
              const float* __restrict__ watt, const float* __restrict__ wp,
              const float* __restrict__ gm1, const float* __restrict__ bm1,
              const float* __restrict__ gm2, const float* __restrict__ bm2,
              const float* __restrict__ gp,  const float* __restrict__ bp,
              const float* __restrict__ w1,  const float* __restrict__ g1,
              const float* __restrict__ b1,  const float* __restrict__ w2,
              const float* __restrict__ g2,  const float* __restrict__ b2,
              ushort* __restrict__ ws)
{
    const int t = blockIdx.x * 256 + threadIdx.x;
    if (t < NFRAG * 64) {
        const int f = t >> 6, l = t & 63, r = l & 15, Q = l >> 4;
        short8v v;
        #pragma unroll
        for (int j = 0; j < 8; ++j) {
            const int k = 8 * Q + j;
            float x;
            if (f == 0)      x = (k < 24) ? wm1[r * 24 + k] : 0.f;
            else if (f == 1) x = (k < 24) ? wm1[(16 + r) * 24 + k] : 0.f;
            else if (f < 6)  { int tt = f - 2;  x = wm2[(16 * tt + r) * 32 + k]; }
            else if (f < 14) { int i = f - 6,  tt = i >> 1, h = i & 1;
                               x = watt[(16 * tt + r) * 64 + 32 * h + k]; }
            else             { int i = f - 14, tt = i >> 1, h = i & 1;
                               x = wp[(16 * tt + r) * 64 + 32 * h + k]; }
            v[j] = (short)f2bf_rne(x);
        }
        ((short8v*)ws)[t] = v;
    } else if (t < NFRAG * 64 + NSCAL * 64) {
        const int i = t - NFRAG * 64;
        const int fld = i >> 6, l = i & 63, r = l & 15;
        float x;
        if (fld == 0)      x = gm1[r] * BN_INV;
        else if (fld == 1) x = bm1[r];
        else if (fld == 2) x = gm1[16 + r] * BN_INV;
        else if (fld == 3) x = bm1[16 + r];
        else if (fld < 8)  x = gm2[16 * (fld - 4) + r] * BN_INV;
        else if (fld < 12) x = bm2[16 * (fld - 8) + r];
        else if (fld < 16) x = gp[16 * (fld - 12) + r] * BN_INV;
        else               x = bp[16 * (fld - 16) + r];
        ((float*)(ws + NFRAG * 64 * 8))[i] = x;
    } else if (t < NFRAG * 64 + NSCAL * 64 + NLSE) {
        const int i = t - NFRAG * 64 - NSCAL * 64;
        float x;
        if (i < 32)       x = w1[i];
        else if (i < 40)  x = g1[i - 32] * BN_INV;
        else if (i < 48)  x = b1[i - 40];
        else if (i < 176) x = w2[i - 48];
        else if (i < 192) x = g2[i - 176] * BN_INV;
        else              x = b2[i - 192];
        ((float*)(ws + NFRAG * 64 * 8))[NSCAL * 64 + i] = x;
    }
}

__global__ __launch_bounds__(64, 4)
void lfa_kernel(const float* __restrict__ coords,
                const float* __restrict__ feats,
                const int*   __restrict__ nidx,
                const ushort* __restrict__ fw,
                float* __restrict__ out)
{
    // one wave per block: X1 4pt x 16 rows x 40 ushorts (pt stride 648)
    //                     X2 16 x 40 ; X3 16 x 76 ; PL aliases X1 tile 0
    __shared__ __align__(16) ushort sX1[2592];
    __shared__ __align__(16) ushort sX2[640];
    __shared__ __align__(16) ushort sX3[1216];   // 8896 B total

    const int l   = threadIdx.x & 63;
    const int r   = l & 15;
    const int Q   = l >> 4;
    const int ptb = blockIdx.x * 8;

    const short8v* FR = (const short8v*)fw;
    const float*   SC = (const float*)(fw + NFRAG * 64 * 8);
    const float*   LW = SC + NSCAL * 64;   // uniform LSE weights (scalar loads)

    // persistent per-lane state (kept minimal for the 128-reg diet):
    const short8v b1f0 = FR[0 * 64 + l];
    const short8v b1f1 = FR[1 * 64 + l];
    const float sm1a = SC[0 * 64 + l], tm1a = SC[1 * 64 + l];
    const float sm1b = SC[2 * 64 + l], tm1b = SC[3 * 64 + l];
    float sm2[4], tm2[4];
    #pragma unroll
    for (int t = 0; t < 4; ++t) {
        sm2[t] = SC[(4 + t) * 64 + l];  tm2[t] = SC[(8 + t) * 64 + l];
    }

    ushort* X1 = sX1;
    ushort* X2 = sX2;
    ushort* X3 = sX3;
    ushort* PL = X1;   // pooled rows (stride 76) alias consumed X1 tile 0

    #pragma unroll 1
    for (int it = 0; it < 2; ++it) {
        const int pt0 = ptb + it * 4;

        // ===== LSE phase: lane = (point Q, neighbor r), streamed row-by-row =====
        {
            const int pt  = pt0 + Q;
            const int nb  = nidx[pt0 * 16 + l];
            const int bb  = pt >> 15;
            const int nbr = (bb << 15) + nb;

            const float cx = coords[pt * 3 + 0], cy = coords[pt * 3 + 1], cz = coords[pt * 3 + 2];
            const float rx = coords[nbr * 3 + 0] - cx;
            const float ry = coords[nbr * 3 + 1] - cy;
            const float rz = coords[nbr * 3 + 2] - cz;
            const float dd = sqrtf(rx * rx + ry * ry + rz * rz);
            float e4[4] = {rx, ry, rz, dd};

            uint4* row = (uint4*)&X1[Q * 648 + r * 40];
            {
                const float4* fp4 = (const float4*)(feats + nbr * 8);
                float4 f0 = fp4[0], f1 = fp4[1];
                row[0] = make_uint4(pk2(f0.x, f0.y), pk2(f0.z, f0.w),
                                    pk2(f1.x, f1.y), pk2(f1.z, f1.w));
                row[3] = make_uint4(0u, 0u, 0u, 0u);
            }
            float h1[8];
            #pragma unroll
            for (int o = 0; o < 8; ++o) {
                float a = 0.f;
                #pragma unroll
                for (int i = 0; i < 4; ++i) a = fmaf(LW[o * 4 + i], e4[i], a);
                h1[o] = fmaxf(fmaf(a, LW[32 + o], LW[40 + o]), 0.f);
            }
            float o8[8];
            #pragma unroll
            for (int o = 0; o < 8; ++o) {
                float a = 0.f;
                #pragma unroll
                for (int i = 0; i < 8; ++i) a = fmaf(LW[48 + o * 8 + i], h1[i], a);
                o8[o] = fmaxf(fmaf(a, LW[176 + o], LW[192 + o]), 0.f);
            }
            row[1] = make_uint4(pk2(o8[0], o8[1]), pk2(o8[2], o8[3]),
                                pk2(o8[4], o8[5]), pk2(o8[6], o8[7]));
            #pragma unroll
            for (int o = 0; o < 8; ++o) {
                float a = 0.f;
                #pragma unroll
                for (int i = 0; i < 8; ++i) a = fmaf(LW[48 + (8 + o) * 8 + i], h1[i], a);
                o8[o] = fmaxf(fmaf(a, LW[184 + o], LW[200 + o]), 0.f);
            }
            row[2] = make_uint4(pk2(o8[0], o8[1]), pk2(o8[2], o8[3]),
                                pk2(o8[4], o8[5]), pk2(o8[6], o8[7]));
        }

        // ===== serial per-point MFMA chains =====
        const float4v z0 = {0.f, 0.f, 0.f, 0.f};
        #pragma unroll 1
        for (int p = 0; p < 4; ++p) {
            int zi = 0;
            asm volatile("" : "+v"(zi));   // defeat LICM re-hoist of weight frags

            const short8v a1 = *(const short8v*)&X1[p * 648 + r * 40 + Q * 8];
            const float4v d1a = __builtin_amdgcn_mfma_f32_16x16x32_bf16(a1, b1f0, z0, 0, 0, 0);
            const float4v d1b = __builtin_amdgcn_mfma_f32_16x16x32_bf16(a1, b1f1, z0, 0, 0, 0);
            #pragma unroll
            for (int q = 0; q < 4; ++q) {
                X2[(4 * Q + q) * 40 + r]      = f2bf(fmaxf(fmaf(d1a[q], sm1a, tm1a), 0.f));
                X2[(4 * Q + q) * 40 + 16 + r] = f2bf(fmaxf(fmaf(d1b[q], sm1b, tm1b), 0.f));
            }
            const short8v a2 = *(const short8v*)&X2[r * 40 + Q * 8];

            float xr[4][4];
            #pragma unroll
            for (int t = 0; t < 4; ++t) {
                const short8v bw = FR[(2 + t) * 64 + l + zi];   // transient
                const float4v d2 = __builtin_amdgcn_mfma_f32_16x16x32_bf16(a2, bw, z0, 0, 0, 0);
                #pragma unroll
                for (int q = 0; q < 4; ++q) {
                    xr[t][q] = fmaxf(fmaf(d2[q], sm2[t], tm2[t]), 0.f);
                    X3[(4 * Q + q) * 76 + 16 * t + r] = f2bf(xr[t][q]);
                }
            }
            const short8v a3l = *(const short8v*)&X3[r * 76 + Q * 8];
            const short8v a3h = *(const short8v*)&X3[r * 76 + 32 + Q * 8];

            float se[4], sn[4];
            #pragma unroll
            for (int t = 0; t < 4; ++t) {
                const short8v bl = FR[(6 + 2 * t) * 64 + l + zi];   // transient
                const short8v bh = FR[(7 + 2 * t) * 64 + l + zi];   // transient
                float4v s = __builtin_amdgcn_mfma_f32_16x16x32_bf16(a3l, bl, z0, 0, 0, 0);
                s         = __builtin_amdgcn_mfma_f32_16x16x32_bf16(a3h, bh, s,  0, 0, 0);
                float e0 = __expf(s[0]), e1 = __expf(s[1]);
                float e2 = __expf(s[2]), e3 = __expf(s[3]);
                se[t] = (e0 + e1) + (e2 + e3);
                sn[t] = fmaf(e0, xr[t][0], e1 * xr[t][1]) + fmaf(e2, xr[t][2], e3 * xr[t][3]);
            }
            #pragma unroll
            for (int t = 0; t < 4; ++t) {
                se[t] += __shfl_xor(se[t], 16, 64);
                sn[t] += __shfl_xor(sn[t], 16, 64);
                se[t] += __shfl_xor(se[t], 32, 64);
                sn[t] += __shfl_xor(sn[t], 32, 64);
            }
            if (l < 16) {
                #pragma unroll
                for (int t = 0; t < 4; ++t)
                    PL[p * 76 + 16 * t + l] = f2bf(__fdividef(sn[t], se[t]));
            }
        }

        // ===== per-iter pool MFMA epilogue (pbf transient; rows 4..15 garbage) =====
        {
            int ze = 0;
            asm volatile("" : "+v"(ze));
            const short8v apl0 = *(const short8v*)&PL[r * 76 + Q * 8];
            const short8v apl1 = *(const short8v*)&PL[r * 76 + 32 + Q * 8];
            float4v dp[4];
            #pragma unroll
            for (int t = 0; t < 4; ++t) {
                const short8v p0 = FR[(14 + 2 * t) * 64 + l + ze];
                const short8v p1 = FR[(15 + 2 * t) * 64 + l + ze];
                float4v d = __builtin_amdgcn_mfma_f32_16x16x32_bf16(apl0, p0, z0, 0, 0, 0);
                d         = __builtin_amdgcn_mfma_f32_16x16x32_bf16(apl1, p1, d,  0, 0, 0);
                dp[t] = d;
            }
            float spv[4], tpv[4];
            #pragma unroll
            for (int t = 0; t < 4; ++t) {
                spv[t] = SC[(12 + t) * 64 + l]; tpv[t] = SC[(16 + t) * 64 + l];
            }
            if (l < 16) {
                #pragma unroll
                for (int q = 0; q < 4; ++q)
                    #pragma unroll
                    for (int t = 0; t < 4; ++t)
                        out[(pt0 + q) * 64 + 16 * t + l] =
                            fmaxf(fmaf(dp[t][q], spv[t], tpv[t]), 0.f);
            }
        }
    }
}

extern "C" void kernel_launch(void* const* d_in, const int* in_sizes, int n_in,
                              void* d_out, int out_size, void* d_ws, size_t ws_size,
                              hipStream_t stream) {
    (void)in_sizes; (void)n_in; (void)ws_size; (void)out_size;
    const float* coords = (const float*)d_in[0];
    const float* feats  = (const float*)d_in[1];
    const int*   nidx   = (const int*)  d_in[2];
    const float* w1  = (const float*)d_in[3];
    const float* g1  = (const float*)d_in[4];
    const float* b1  = (const float*)d_in[5];
    const float* w2  = (const float*)d_in[6];
    const float* g2  = (const float*)d_in[7];
    const float* b2  = (const float*)d_in[8];
    const float* wm1 = (const float*)d_in[9];
    const float* gm1 = (const float*)d_in[10];
    const float* bm1 = (const float*)d_in[11];
    const float* wm2 = (const float*)d_in[12];
    const float* gm2 = (const float*)d_in[13];
    const float* bm2 = (const float*)d_in[14];
    const float* watt = (const float*)d_in[15];
    const float* wp  = (const float*)d_in[16];
    const float* gp  = (const float*)d_in[17];
    const float* bp  = (const float*)d_in[18];
    float* out = (float*)d_out;
    ushort* ws = (ushort*)d_ws;

    lfa_pack<<<dim3(12), dim3(256), 0, stream>>>(wm1, wm2, watt, wp,
                                                 gm1, bm1, gm2, bm2, gp, bp,
                                                 w1, g1, b1, w2, g2, b2, ws);
    lfa_kernel<<<dim3(8192), dim3(64), 0, stream>>>(coords, feats, nidx, ws, out);
}

// Round 13
// 61.987 us; speedup vs baseline: 1.2488x; 1.2488x over previous
//
#include <hip/hip_runtime.h>
#include <hip/hip_bf16.h>

// LocalFeatureAggregation: B=2, N=32768, K=16, CIN=8, COUT=64
// MFMA version 9 = round-11 (best: 68 µs) + instruction diet:
//  (a) channel-permuted LDS bridges: X2 written as b32 pairs (pos 2o<->ch o,
//      2o+1<->ch 16+o), X3/PL written as b64 quads (pos 4r+t <-> ch 16t+r);
//      inverse permutation baked into b2f/b3f/pbf fragments by lfa_pack.
//  (b) att weights prescaled by log2(e) -> raw v_exp_f32 (exp2), no v_mul.
//  (c) all-lane softmax tail (lane handles t=Q via cndmask), no divergence.
// 1-wave blocks, launch_bounds(64,2) (proven no-spill; occupancy experiments
// r5/r9/r12 all showed higher residency loses to lost ILP/spill).
// Grid = 4096 blocks x 4 iters x 4 points; deferred pool epilogue.

typedef __attribute__((ext_vector_type(8))) short short8v;
typedef __attribute__((ext_vector_type(4))) float float4v;

#define BN_INV 0.9999950000374997f
#define LOG2E  1.4426950408889634f
#define NFRAG 22
#define NSCAL 20

// cheap float->bf16, round-half-up (1-ulp-on-ties vs RNE; inputs finite)
__device__ __forceinline__ ushort f2bf(float f) {
    return (ushort)((__float_as_uint(f) + 0x8000u) >> 16);
}
// pack two: low half = bf16(a), high half = bf16(b)
__device__ __forceinline__ uint pk2(float a, float b) {
    return __builtin_amdgcn_perm(__float_as_uint(b) + 0x8000u,
                                 __float_as_uint(a) + 0x8000u, 0x07060302u);
}
__device__ __forceinline__ ushort f2bf_rne(float f) {
    __hip_bfloat16 h = __float2bfloat16(f);
    return __builtin_bit_cast(ushort, h);
}
__device__ __forceinline__ float fexp2(float x) {
#if __has_builtin(__builtin_amdgcn_exp2f)
    return __builtin_amdgcn_exp2f(x);
#else
    return exp2f(x);
#endif
}

// ---- setup: pack per-lane MFMA B-fragments + scale/shift into d_ws ----
// layout: [NFRAG][64] x 16B fragments, then [NSCAL][64] x f32.
// frag order: 0 b1f0, 1 b1f1, 2-5 b2f[t], 6-13 b3f[2t+h], 14-21 pbf[2t+h].
// b2f k-columns permuted by ch2(p) = (p>>1) + 16*(p&1)  (X2 pair layout);
// b3f/pbf k-columns permuted by ch3(p) = 16*(p&3) + (p>>2) (X3/PL quad layout);
// b3f additionally scaled by log2(e) for the exp2 softmax.
__global__ __launch_bounds__(256)
void lfa_pack(const float* __restrict__ wm1, const float* __restrict__ wm2,
              const float* __restrict__ watt, const float* __restrict__ wp,
              const float* __restrict__ gm1, const float* __restrict__ bm1,
              const float* __restrict__ gm2, const float* __restrict__ bm2,
              const float* __restrict__ gp,  const float* __restrict__ bp,
              ushort* __restrict__ ws)
{
    const int t = blockIdx.x * 256 + threadIdx.x;
    if (t < NFRAG * 64) {
        const int f = t >> 6, l = t & 63, r = l & 15, Q = l >> 4;
        short8v v;
        #pragma unroll
        for (int j = 0; j < 8; ++j) {
            const int k = 8 * Q + j;
            float x;
            if (f == 0)      x = (k < 24) ? wm1[r * 24 + k] : 0.f;
            else if (f == 1) x = (k < 24) ? wm1[(16 + r) * 24 + k] : 0.f;
            else if (f < 6)  { int tt = f - 2;
                               int c = (k >> 1) + 16 * (k & 1);
                               x = wm2[(16 * tt + r) * 32 + c]; }
            else if (f < 14) { int i = f - 6,  tt = i >> 1, h = i & 1;
                               int p = 32 * h + k;
                               int c = 16 * (p & 3) + (p >> 2);
                               x = watt[(16 * tt + r) * 64 + c] * LOG2E; }
            else             { int i = f - 14, tt = i >> 1, h = i & 1;
                               int p = 32 * h + k;
                               int c = 16 * (p & 3) + (p >> 2);
                               x = wp[(16 * tt + r) * 64 + c]; }
            v[j] = (short)f2bf_rne(x);
        }
        ((short8v*)ws)[t] = v;
    } else if (t < NFRAG * 64 + NSCAL * 64) {
        const int i = t - NFRAG * 64;
        const int fld = i >> 6, l = i & 63, r = l & 15;
        float x;
        if (fld == 0)      x = gm1[r] * BN_INV;
        else if (fld == 1) x = bm1[r];
        else if (fld == 2) x = gm1[16 + r] * BN_INV;
        else if (fld == 3) x = bm1[16 + r];
        else if (fld < 8)  x = gm2[16 * (fld - 4) + r] * BN_INV;
        else if (fld < 12) x = bm2[16 * (fld - 8) + r];
        else if (fld < 16) x = gp[16 * (fld - 12) + r] * BN_INV;
        else               x = bp[16 * (fld - 16) + r];
        ((float*)(ws + NFRAG * 64 * 8))[i] = x;
    }
}

__global__ __launch_bounds__(64, 2)
void lfa_kernel(const float* __restrict__ coords,
                const float* __restrict__ feats,
                const int*   __restrict__ nidx,
                const float* __restrict__ w1, const float* __restrict__ g1, const float* __restrict__ b1,
                const float* __restrict__ w2, const float* __restrict__ g2, const float* __restrict__ b2,
                const ushort* __restrict__ fw,
                float* __restrict__ out)
{
    // one wave per block: X1 4pt x 16 rows x 40 ushorts (pt stride 648)
    //                     X2 2 tiles x 16 x 40 (X3B aliases this, stride 72)
    //                     X3A 16 x 72 ; PL 16 rows x 72 (all 16 block points)
    __shared__ __align__(16) ushort sX1[2592];
    __shared__ __align__(16) ushort sX2[1280];
    __shared__ __align__(16) ushort sX3[1152];
    __shared__ __align__(16) ushort sPL[1152];   // 12352 B total

    const int l   = threadIdx.x & 63;
    const int r   = l & 15;
    const int Q   = l >> 4;
    const int ptb = blockIdx.x * 16;

    // ---- persistent fragments (b1/b2/b3; pool stuff loaded at epilogue) ----
    const short8v* FR = (const short8v*)fw;
    const float*   SC = (const float*)(fw + NFRAG * 64 * 8);
    const short8v b1f0 = FR[0 * 64 + l];
    const short8v b1f1 = FR[1 * 64 + l];
    short8v b2f[4], b3f[8];
    #pragma unroll
    for (int t = 0; t < 4; ++t) b2f[t] = FR[(2 + t) * 64 + l];
    #pragma unroll
    for (int i = 0; i < 8; ++i) b3f[i] = FR[(6 + i) * 64 + l];

    const float sm1a = SC[0 * 64 + l], tm1a = SC[1 * 64 + l];
    const float sm1b = SC[2 * 64 + l], tm1b = SC[3 * 64 + l];
    float sm2[4], tm2[4];
    #pragma unroll
    for (int t = 0; t < 4; ++t) {
        sm2[t] = SC[(4 + t) * 64 + l];  tm2[t] = SC[(8 + t) * 64 + l];
    }

    ushort* X1  = sX1;
    ushort* X2A = sX2;
    ushort* X2B = X2A + 640;
    ushort* X3A = sX3;
    ushort* X3B = sX2;            // 16 x 72 = 1152 <= 1280, aliases X2A/X2B

    // ---- prologue gather (it = 0): exposed once per block ----
    float cx, cy, cz, nx, ny, nz;
    float4 f0v, f1v;
    {
        const int pt0n = ptb;
        const int pt   = pt0n + Q;
        const int nb   = nidx[pt0n * 16 + l];
        const int bb   = pt >> 15;
        const int nbr  = (bb << 15) + nb;
        cx = coords[pt * 3 + 0];  cy = coords[pt * 3 + 1];  cz = coords[pt * 3 + 2];
        nx = coords[nbr * 3 + 0]; ny = coords[nbr * 3 + 1]; nz = coords[nbr * 3 + 2];
        const float4* fp4 = (const float4*)(feats + nbr * 8);
        f0v = fp4[0]; f1v = fp4[1];
    }

    #pragma unroll 1
    for (int it = 0; it < 4; ++it) {
        // ===== LSE phase from prefetched values: lane = (point Q, nbr r) =====
        {
            const float rx = nx - cx;
            const float ry = ny - cy;
            const float rz = nz - cz;
            const float dd = sqrtf(rx * rx + ry * ry + rz * rz);
            float e4[4] = {rx, ry, rz, dd};

            float x24[24];
            x24[0] = f0v.x; x24[1] = f0v.y; x24[2] = f0v.z; x24[3] = f0v.w;
            x24[4] = f1v.x; x24[5] = f1v.y; x24[6] = f1v.z; x24[7] = f1v.w;

            float h1[8];
            #pragma unroll
            for (int o = 0; o < 8; ++o) {
                float a = 0.f;
                #pragma unroll
                for (int i = 0; i < 4; ++i) a = fmaf(w1[o * 4 + i], e4[i], a);
                h1[o] = fmaxf(fmaf(a, g1[o] * BN_INV, b1[o]), 0.f);
            }
            #pragma unroll
            for (int o = 0; o < 16; ++o) {
                float a = 0.f;
                #pragma unroll
                for (int i = 0; i < 8; ++i) a = fmaf(w2[o * 8 + i], h1[i], a);
                x24[8 + o] = fmaxf(fmaf(a, g2[o] * BN_INV, b2[o]), 0.f);
            }
            uint4* row = (uint4*)&X1[Q * 648 + r * 40];
            row[0] = make_uint4(pk2(x24[0],  x24[1]),  pk2(x24[2],  x24[3]),
                                pk2(x24[4],  x24[5]),  pk2(x24[6],  x24[7]));
            row[1] = make_uint4(pk2(x24[8],  x24[9]),  pk2(x24[10], x24[11]),
                                pk2(x24[12], x24[13]), pk2(x24[14], x24[15]));
            row[2] = make_uint4(pk2(x24[16], x24[17]), pk2(x24[18], x24[19]),
                                pk2(x24[20], x24[21]), pk2(x24[22], x24[23]));
            row[3] = make_uint4(0u, 0u, 0u, 0u);
        }

        // ===== prefetch gather for it+1 (latency hidden under pair phase) =====
        if (it < 3) {
            const int pt0n = ptb + (it + 1) * 4;
            const int pt   = pt0n + Q;
            const int nb   = nidx[pt0n * 16 + l];
            const int bb   = pt >> 15;
            const int nbr  = (bb << 15) + nb;
            cx = coords[pt * 3 + 0];  cy = coords[pt * 3 + 1];  cz = coords[pt * 3 + 2];
            nx = coords[nbr * 3 + 0]; ny = coords[nbr * 3 + 1]; nz = coords[nbr * 3 + 2];
            const float4* fp4 = (const float4*)(feats + nbr * 8);
            f0v = fp4[0]; f1v = fp4[1];
        }

        // ===== paired per-point MFMA chains (points 2pp, 2pp+1) =====
        const float4v z0 = {0.f, 0.f, 0.f, 0.f};
        #pragma unroll 1
        for (int pp = 0; pp < 2; ++pp) {
            ushort* X1A = X1 + (2 * pp) * 648;
            ushort* X1B = X1A + 648;
            const short8v a1A = *(const short8v*)&X1A[r * 40 + Q * 8];
            const short8v a1B = *(const short8v*)&X1B[r * 40 + Q * 8];
            const float4v d1aA = __builtin_amdgcn_mfma_f32_16x16x32_bf16(a1A, b1f0, z0, 0, 0, 0);
            const float4v d1bA = __builtin_amdgcn_mfma_f32_16x16x32_bf16(a1A, b1f1, z0, 0, 0, 0);
            const float4v d1aB = __builtin_amdgcn_mfma_f32_16x16x32_bf16(a1B, b1f0, z0, 0, 0, 0);
            const float4v d1bB = __builtin_amdgcn_mfma_f32_16x16x32_bf16(a1B, b1f1, z0, 0, 0, 0);
            // X2: paired-channel b32 writes (pos 2o <-> ch o, 2o+1 <-> ch 16+o)
            #pragma unroll
            for (int q = 0; q < 4; ++q) {
                const float vaA = fmaxf(fmaf(d1aA[q], sm1a, tm1a), 0.f);
                const float vbA = fmaxf(fmaf(d1bA[q], sm1b, tm1b), 0.f);
                const float vaB = fmaxf(fmaf(d1aB[q], sm1a, tm1a), 0.f);
                const float vbB = fmaxf(fmaf(d1bB[q], sm1b, tm1b), 0.f);
                *(uint*)&X2A[(4 * Q + q) * 40 + 2 * r] = pk2(vaA, vbA);
                *(uint*)&X2B[(4 * Q + q) * 40 + 2 * r] = pk2(vaB, vbB);
            }
            const short8v a2A = *(const short8v*)&X2A[r * 40 + Q * 8];
            const short8v a2B = *(const short8v*)&X2B[r * 40 + Q * 8];
            float4v d2A[4], d2B[4];
            #pragma unroll
            for (int t = 0; t < 4; ++t) {
                d2A[t] = __builtin_amdgcn_mfma_f32_16x16x32_bf16(a2A, b2f[t], z0, 0, 0, 0);
                d2B[t] = __builtin_amdgcn_mfma_f32_16x16x32_bf16(a2B, b2f[t], z0, 0, 0, 0);
            }
            float xrA[4][4], xrB[4][4];
            #pragma unroll
            for (int t = 0; t < 4; ++t)
                #pragma unroll
                for (int q = 0; q < 4; ++q) {
                    xrA[t][q] = fmaxf(fmaf(d2A[t][q], sm2[t], tm2[t]), 0.f);
                    xrB[t][q] = fmaxf(fmaf(d2B[t][q], sm2[t], tm2[t]), 0.f);
                }

            // X3: quad-channel b64 writes (pos 4r+t <-> ch 16t+r)
            #pragma unroll
            for (int q = 0; q < 4; ++q) {
                *(uint2*)&X3A[(4 * Q + q) * 72 + 4 * r] =
                    make_uint2(pk2(xrA[0][q], xrA[1][q]), pk2(xrA[2][q], xrA[3][q]));
                *(uint2*)&X3B[(4 * Q + q) * 72 + 4 * r] =
                    make_uint2(pk2(xrB[0][q], xrB[1][q]), pk2(xrB[2][q], xrB[3][q]));
            }
            const short8v a3lA = *(const short8v*)&X3A[r * 72 + Q * 8];
            const short8v a3hA = *(const short8v*)&X3A[r * 72 + 32 + Q * 8];
            const short8v a3lB = *(const short8v*)&X3B[r * 72 + Q * 8];
            const short8v a3hB = *(const short8v*)&X3B[r * 72 + 32 + Q * 8];

            // ---- interleaved ATT + softmax (scores prescaled by log2e) ----
            float seA[4], snA[4], seB[4], snB[4];
            #pragma unroll
            for (int t = 0; t < 4; ++t) {
                float4v sA = __builtin_amdgcn_mfma_f32_16x16x32_bf16(a3lA, b3f[t * 2],     z0, 0, 0, 0);
                sA         = __builtin_amdgcn_mfma_f32_16x16x32_bf16(a3hA, b3f[t * 2 + 1], sA, 0, 0, 0);
                float4v sB = __builtin_amdgcn_mfma_f32_16x16x32_bf16(a3lB, b3f[t * 2],     z0, 0, 0, 0);
                sB         = __builtin_amdgcn_mfma_f32_16x16x32_bf16(a3hB, b3f[t * 2 + 1], sB, 0, 0, 0);
                float e0A = fexp2(sA[0]), e1A = fexp2(sA[1]);
                float e2A = fexp2(sA[2]), e3A = fexp2(sA[3]);
                float e0B = fexp2(sB[0]), e1B = fexp2(sB[1]);
                float e2B = fexp2(sB[2]), e3B = fexp2(sB[3]);
                seA[t] = (e0A + e1A) + (e2A + e3A);
                snA[t] = fmaf(e0A, xrA[t][0], e1A * xrA[t][1]) + fmaf(e2A, xrA[t][2], e3A * xrA[t][3]);
                seB[t] = (e0B + e1B) + (e2B + e3B);
                snB[t] = fmaf(e0B, xrB[t][0], e1B * xrB[t][1]) + fmaf(e2B, xrB[t][2], e3B * xrB[t][3]);
            }
            #pragma unroll
            for (int t = 0; t < 4; ++t) {
                seA[t] += __shfl_xor(seA[t], 16, 64);
                snA[t] += __shfl_xor(snA[t], 16, 64);
                seB[t] += __shfl_xor(seB[t], 16, 64);
                snB[t] += __shfl_xor(snB[t], 16, 64);
                seA[t] += __shfl_xor(seA[t], 32, 64);
                snA[t] += __shfl_xor(snA[t], 32, 64);
                seB[t] += __shfl_xor(seB[t], 32, 64);
                snB[t] += __shfl_xor(snB[t], 32, 64);
            }
            // all-lane tail: lane handles t=Q, channel 16Q+r -> PL pos 4r+Q
            {
                const float snqA = (Q == 0) ? snA[0] : (Q == 1) ? snA[1] : (Q == 2) ? snA[2] : snA[3];
                const float seqA = (Q == 0) ? seA[0] : (Q == 1) ? seA[1] : (Q == 2) ? seA[2] : seA[3];
                const float snqB = (Q == 0) ? snB[0] : (Q == 1) ? snB[1] : (Q == 2) ? snB[2] : snB[3];
                const float seqB = (Q == 0) ? seB[0] : (Q == 1) ? seB[1] : (Q == 2) ? seB[2] : seB[3];
                sPL[(4 * it + 2 * pp) * 72 + 4 * r + Q]     = f2bf(__fdividef(snqA, seqA));
                sPL[(4 * it + 2 * pp + 1) * 72 + 4 * r + Q] = f2bf(__fdividef(snqB, seqB));
            }
        }
    }

    // ===== ONE pool MFMA epilogue for all 16 block points (all lanes valid) =====
    short8v pbf[8];
    #pragma unroll
    for (int i = 0; i < 8; ++i) pbf[i] = FR[(14 + i) * 64 + l];
    float spv[4], tpv[4];
    #pragma unroll
    for (int t = 0; t < 4; ++t) {
        spv[t] = SC[(12 + t) * 64 + l]; tpv[t] = SC[(16 + t) * 64 + l];
    }
    const float4v z0 = {0.f, 0.f, 0.f, 0.f};
    const short8v apl0 = *(const short8v*)&sPL[r * 72 + Q * 8];
    const short8v apl1 = *(const short8v*)&sPL[r * 72 + 32 + Q * 8];
    float4v dp[4];
    #pragma unroll
    for (int t = 0; t < 4; ++t) {
        float4v d = __builtin_amdgcn_mfma_f32_16x16x32_bf16(apl0, pbf[t * 2],     z0, 0, 0, 0);
        d         = __builtin_amdgcn_mfma_f32_16x16x32_bf16(apl1, pbf[t * 2 + 1], d,  0, 0, 0);
        dp[t] = d;
    }
    // D: row = 4Q+q = block point, col = 16t+r = output channel -> dense stores
    #pragma unroll
    for (int q = 0; q < 4; ++q)
        #pragma unroll
        for (int t = 0; t < 4; ++t)
            out[(ptb + 4 * Q + q) * 64 + 16 * t + r] =
                fmaxf(fmaf(dp[t][q], spv[t], tpv[t]), 0.f);
}

extern "C" void kernel_launch(void* const* d_in, const int* in_sizes, int n_in,
                              void* d_out, int out_size, void* d_ws, size_t ws_size,
                              hipStream_t stream) {
    (void)in_sizes; (void)n_in; (void)ws_size; (void)out_size;
    const float* coords = (const float*)d_in[0];
    const float* feats  = (const float*)d_in[1];
    const int*   nidx   = (const int*)  d_in[2];
    const float* w1  = (const float*)d_in[3];
    const float* g1  = (const float*)d_in[4];
    const float* b1  = (const float*)d_in[5];
    const float* w2  = (const float*)d_in[6];
    const float* g2  = (const float*)d_in[7];
    const float* b2  = (const float*)d_in[8];
    const float* wm1 = (const float*)d_in[9];
    const float* gm1 = (const float*)d_in[10];
    const float* bm1 = (const float*)d_in[11];
    const float* wm2 = (const float*)d_in[12];
    const float* gm2 = (const float*)d_in[13];
    const float* bm2 = (const float*)d_in[14];
    const float* watt = (const float*)d_in[15];
    const float* wp  = (const float*)d_in[16];
    const float* gp  = (const float*)d_in[17];
    const float* bp  = (const float*)d_in[18];
    float* out = (float*)d_out;
    ushort* ws = (ushort*)d_ws;

    lfa_pack<<<dim3(11), dim3(256), 0, stream>>>(wm1, wm2, watt, wp,
                                                 gm1, bm1, gm2, bm2, gp, bp, ws);
    lfa_kernel<<<dim3(4096), dim3(64), 0, stream>>>(coords, feats, nidx,
                                                    w1, g1, b1, w2, g2, b2,
                                                    ws, out);
}

// Round 14
// 51.561 us; speedup vs baseline: 1.5013x; 1.2022x over previous
//
#include <hip/hip_runtime.h>
#include <hip/hip_bf16.h>

// LocalFeatureAggregation: B=2, N=32768, K=16, CIN=8, COUT=64
// MFMA version 10 = round-13 (62 µs) + LSE2-as-MFMA + setprio:
//  (a) LSE layer-2 (8->16, was 128 scalar FMA/lane) now a swapped-operand
//      MFMA per point: A = prescaled w2 fragment (BN folded into rows at
//      pack time), B = h1 columns read from an LDS transpose buffer Xh
//      (aliases sX2; Q!=0 lanes read zeroed pad rows 64..79). D lands as
//      lane (r,Q) -> out-chs 4Q..4Q+3 of neighbor-row r -> one uint2 store
//      into X1's enc slot. Kills x24[24] (-24 VGPRs, ~-105 insts/lane/iter).
//  (b) s_setprio(1) around the pair-phase chain (independent 1-wave blocks
//      = attn-like structure where setprio measured +4-7%).
// Grid = 4096 blocks x 4 iters x 4 points; deferred pool epilogue.

typedef __attribute__((ext_vector_type(8))) short short8v;
typedef __attribute__((ext_vector_type(4))) float float4v;

#define BN_INV 0.9999950000374997f
#define LOG2E  1.4426950408889634f
#define NFRAG 23
#define NSCAL 24

// cheap float->bf16, round-half-up (1-ulp-on-ties vs RNE; inputs finite)
__device__ __forceinline__ ushort f2bf(float f) {
    return (ushort)((__float_as_uint(f) + 0x8000u) >> 16);
}
// pack two: low half = bf16(a), high half = bf16(b)
__device__ __forceinline__ uint pk2(float a, float b) {
    return __builtin_amdgcn_perm(__float_as_uint(b) + 0x8000u,
                                 __float_as_uint(a) + 0x8000u, 0x07060302u);
}
__device__ __forceinline__ ushort f2bf_rne(float f) {
    __hip_bfloat16 h = __float2bfloat16(f);
    return __builtin_bit_cast(ushort, h);
}
__device__ __forceinline__ float fexp2(float x) {
#if __has_builtin(__builtin_amdgcn_exp2f)
    return __builtin_amdgcn_exp2f(x);
#else
    return exp2f(x);
#endif
}

// ---- setup: pack per-lane MFMA B-fragments + scale/shift into d_ws ----
// layout: [NFRAG][64] x 16B fragments, then [NSCAL][64] x f32.
// frag order: 0 b1f0, 1 b1f1, 2-5 b2f[t], 6-13 b3f[2t+h], 14-21 pbf[2t+h],
//             22 w2f (LSE2 A-operand, rows prescaled by g2*BN_INV, Q!=0 -> 0).
// b2f k-columns permuted by ch2(p) = (p>>1) + 16*(p&1)  (X2 pair layout);
// b3f/pbf k-columns permuted by ch3(p) = 16*(p&3) + (p>>2) (X3/PL quad layout);
// b3f additionally scaled by log2(e) for the exp2 softmax.
// scalars: 0-19 as before; 20-23: b2lse[4Q+q] (LSE2 bias per-lane).
__global__ __launch_bounds__(256)
void lfa_pack(const float* __restrict__ wm1, const float* __restrict__ wm2,
              const float* __restrict__ watt, const float* __restrict__ wp,
              const float* __restrict__ gm1, const float* __restrict__ bm1,
              const float* __restrict__ gm2, const float* __restrict__ bm2,
              const float* __restrict__ gp,  const float* __restrict__ bp,
              const float* __restrict__ w2,  const float* __restrict__ g2,
              const float* __restrict__ b2,
              ushort* __restrict__ ws)
{
    const int t = blockIdx.x * 256 + threadIdx.x;
    if (t < NFRAG * 64) {
        const int f = t >> 6, l = t & 63, r = l & 15, Q = l >> 4;
        short8v v;
        #pragma unroll
        for (int j = 0; j < 8; ++j) {
            const int k = 8 * Q + j;
            float x;
            if (f == 0)      x = (k < 24) ? wm1[r * 24 + k] : 0.f;
            else if (f == 1) x = (k < 24) ? wm1[(16 + r) * 24 + k] : 0.f;
            else if (f < 6)  { int tt = f - 2;
                               int c = (k >> 1) + 16 * (k & 1);
                               x = wm2[(16 * tt + r) * 32 + c]; }
            else if (f < 14) { int i = f - 6,  tt = i >> 1, h = i & 1;
                               int p = 32 * h + k;
                               int c = 16 * (p & 3) + (p >> 2);
                               x = watt[(16 * tt + r) * 64 + c] * LOG2E; }
            else if (f < 22) { int i = f - 14, tt = i >> 1, h = i & 1;
                               int p = 32 * h + k;
                               int c = 16 * (p & 3) + (p >> 2);
                               x = wp[(16 * tt + r) * 64 + c]; }
            else             { x = (k < 8) ? w2[r * 8 + k] * (g2[r] * BN_INV) : 0.f; }
            v[j] = (short)f2bf_rne(x);
        }
        ((short8v*)ws)[t] = v;
    } else if (t < NFRAG * 64 + NSCAL * 64) {
        const int i = t - NFRAG * 64;
        const int fld = i >> 6, l = i & 63, r = l & 15, Q = l >> 4;
        float x;
        if (fld == 0)      x = gm1[r] * BN_INV;
        else if (fld == 1) x = bm1[r];
        else if (fld == 2) x = gm1[16 + r] * BN_INV;
        else if (fld == 3) x = bm1[16 + r];
        else if (fld < 8)  x = gm2[16 * (fld - 4) + r] * BN_INV;
        else if (fld < 12) x = bm2[16 * (fld - 8) + r];
        else if (fld < 16) x = gp[16 * (fld - 12) + r] * BN_INV;
        else if (fld < 20) x = bp[16 * (fld - 16) + r];
        else               x = b2[4 * Q + (fld - 20)];
        ((float*)(ws + NFRAG * 64 * 8))[i] = x;
    }
}

__global__ __launch_bounds__(64, 2)
void lfa_kernel(const float* __restrict__ coords,
                const float* __restrict__ feats,
                const int*   __restrict__ nidx,
                const float* __restrict__ w1, const float* __restrict__ g1, const float* __restrict__ b1,
                const ushort* __restrict__ fw,
                float* __restrict__ out)
{
    // one wave per block: X1 4pt x 16 rows x 40 ushorts (pt stride 648)
    //                     sX2: Xh transpose buf (LSE) / X2 pair tiles / X3B
    //                     X3A 16 x 72 ; PL 16 rows x 72 (all 16 block points)
    __shared__ __align__(16) ushort sX1[2592];
    __shared__ __align__(16) ushort sX2[1280];
    __shared__ __align__(16) ushort sX3[1152];
    __shared__ __align__(16) ushort sPL[1152];   // 12352 B total

    const int l   = threadIdx.x & 63;
    const int r   = l & 15;
    const int Q   = l >> 4;
    const int ptb = blockIdx.x * 16;

    // ---- persistent fragments (b1/b2/b3/w2f; pool stuff loaded at epilogue) ----
    const short8v* FR = (const short8v*)fw;
    const float*   SC = (const float*)(fw + NFRAG * 64 * 8);
    const short8v b1f0 = FR[0 * 64 + l];
    const short8v b1f1 = FR[1 * 64 + l];
    const short8v w2f  = FR[22 * 64 + l];
    short8v b2f[4], b3f[8];
    #pragma unroll
    for (int t = 0; t < 4; ++t) b2f[t] = FR[(2 + t) * 64 + l];
    #pragma unroll
    for (int i = 0; i < 8; ++i) b3f[i] = FR[(6 + i) * 64 + l];

    const float sm1a = SC[0 * 64 + l], tm1a = SC[1 * 64 + l];
    const float sm1b = SC[2 * 64 + l], tm1b = SC[3 * 64 + l];
    float sm2[4], tm2[4], t2l[4];
    #pragma unroll
    for (int t = 0; t < 4; ++t) {
        sm2[t] = SC[(4 + t) * 64 + l];  tm2[t] = SC[(8 + t) * 64 + l];
        t2l[t] = SC[(20 + t) * 64 + l];
    }

    ushort* X1  = sX1;
    ushort* X2A = sX2;
    ushort* X2B = X2A + 640;
    ushort* X3A = sX3;
    ushort* X3B = sX2;            // 16 x 72 = 1152 <= 1280, aliases X2A/X2B
    ushort* Xh  = sX2;            // 80 rows x 8 ushorts (LSE transpose buf)

    // ---- prologue gather (it = 0): exposed once per block ----
    float cx, cy, cz, nx, ny, nz;
    float4 f0v, f1v;
    {
        const int pt0n = ptb;
        const int pt   = pt0n + Q;
        const int nb   = nidx[pt0n * 16 + l];
        const int bb   = pt >> 15;
        const int nbr  = (bb << 15) + nb;
        cx = coords[pt * 3 + 0];  cy = coords[pt * 3 + 1];  cz = coords[pt * 3 + 2];
        nx = coords[nbr * 3 + 0]; ny = coords[nbr * 3 + 1]; nz = coords[nbr * 3 + 2];
        const float4* fp4 = (const float4*)(feats + nbr * 8);
        f0v = fp4[0]; f1v = fp4[1];
    }

    const float4v z0 = {0.f, 0.f, 0.f, 0.f};

    #pragma unroll 1
    for (int it = 0; it < 4; ++it) {
        // ===== LSE phase: lane = (point Q, nbr r); layer 2 via swapped MFMA =====
        {
            // zero Xh pad rows 64..79 (clobbered by X3B last iter)
            *(uint*)&Xh[512 + 2 * l] = 0u;

            const float rx = nx - cx;
            const float ry = ny - cy;
            const float rz = nz - cz;
            const float dd = sqrtf(rx * rx + ry * ry + rz * rz);
            float e4[4] = {rx, ry, rz, dd};

            // nf -> X1 row slots 0..7, zero pad 24..31
            uint4* row = (uint4*)&X1[Q * 648 + r * 40];
            row[0] = make_uint4(pk2(f0v.x, f0v.y), pk2(f0v.z, f0v.w),
                                pk2(f1v.x, f1v.y), pk2(f1v.z, f1v.w));
            row[3] = make_uint4(0u, 0u, 0u, 0u);

            float h1[8];
            #pragma unroll
            for (int o = 0; o < 8; ++o) {
                float a = 0.f;
                #pragma unroll
                for (int i = 0; i < 4; ++i) a = fmaf(w1[o * 4 + i], e4[i], a);
                h1[o] = fmaxf(fmaf(a, g1[o] * BN_INV, b1[o]), 0.f);
            }
            // h1 -> Xh[l] (row l = this lane's (pt,k) row)
            *(uint4*)&Xh[l * 8] = make_uint4(pk2(h1[0], h1[1]), pk2(h1[2], h1[3]),
                                             pk2(h1[4], h1[5]), pk2(h1[6], h1[7]));
            // per point t: one swapped MFMA -> enc16 into X1
            #pragma unroll
            for (int t = 0; t < 4; ++t) {
                const int rowi = (Q == 0) ? (16 * t + r) : (64 + r);
                const short8v bh = *(const short8v*)&Xh[rowi * 8];
                const float4v de = __builtin_amdgcn_mfma_f32_16x16x32_bf16(w2f, bh, z0, 0, 0, 0);
                const float v0 = fmaxf(de[0] + t2l[0], 0.f);
                const float v1 = fmaxf(de[1] + t2l[1], 0.f);
                const float v2 = fmaxf(de[2] + t2l[2], 0.f);
                const float v3 = fmaxf(de[3] + t2l[3], 0.f);
                *(uint2*)&X1[t * 648 + r * 40 + 8 + 4 * Q] =
                    make_uint2(pk2(v0, v1), pk2(v2, v3));
            }
        }

        // ===== prefetch gather for it+1 (latency hidden under pair phase) =====
        if (it < 3) {
            const int pt0n = ptb + (it + 1) * 4;
            const int pt   = pt0n + Q;
            const int nb   = nidx[pt0n * 16 + l];
            const int bb   = pt >> 15;
            const int nbr  = (bb << 15) + nb;
            cx = coords[pt * 3 + 0];  cy = coords[pt * 3 + 1];  cz = coords[pt * 3 + 2];
            nx = coords[nbr * 3 + 0]; ny = coords[nbr * 3 + 1]; nz = coords[nbr * 3 + 2];
            const float4* fp4 = (const float4*)(feats + nbr * 8);
            f0v = fp4[0]; f1v = fp4[1];
        }

        // ===== paired per-point MFMA chains (points 2pp, 2pp+1) =====
        __builtin_amdgcn_s_setprio(1);
        #pragma unroll 1
        for (int pp = 0; pp < 2; ++pp) {
            ushort* X1A = X1 + (2 * pp) * 648;
            ushort* X1B = X1A + 648;
            const short8v a1A = *(const short8v*)&X1A[r * 40 + Q * 8];
            const short8v a1B = *(const short8v*)&X1B[r * 40 + Q * 8];
            const float4v d1aA = __builtin_amdgcn_mfma_f32_16x16x32_bf16(a1A, b1f0, z0, 0, 0, 0);
            const float4v d1bA = __builtin_amdgcn_mfma_f32_16x16x32_bf16(a1A, b1f1, z0, 0, 0, 0);
            const float4v d1aB = __builtin_amdgcn_mfma_f32_16x16x32_bf16(a1B, b1f0, z0, 0, 0, 0);
            const float4v d1bB = __builtin_amdgcn_mfma_f32_16x16x32_bf16(a1B, b1f1, z0, 0, 0, 0);
            // X2: paired-channel b32 writes (pos 2o <-> ch o, 2o+1 <-> ch 16+o)
            #pragma unroll
            for (int q = 0; q < 4; ++q) {
                const float vaA = fmaxf(fmaf(d1aA[q], sm1a, tm1a), 0.f);
                const float vbA = fmaxf(fmaf(d1bA[q], sm1b, tm1b), 0.f);
                const float vaB = fmaxf(fmaf(d1aB[q], sm1a, tm1a), 0.f);
                const float vbB = fmaxf(fmaf(d1bB[q], sm1b, tm1b), 0.f);
                *(uint*)&X2A[(4 * Q + q) * 40 + 2 * r] = pk2(vaA, vbA);
                *(uint*)&X2B[(4 * Q + q) * 40 + 2 * r] = pk2(vaB, vbB);
            }
            const short8v a2A = *(const short8v*)&X2A[r * 40 + Q * 8];
            const short8v a2B = *(const short8v*)&X2B[r * 40 + Q * 8];
            float4v d2A[4], d2B[4];
            #pragma unroll
            for (int t = 0; t < 4; ++t) {
                d2A[t] = __builtin_amdgcn_mfma_f32_16x16x32_bf16(a2A, b2f[t], z0, 0, 0, 0);
                d2B[t] = __builtin_amdgcn_mfma_f32_16x16x32_bf16(a2B, b2f[t], z0, 0, 0, 0);
            }
            float xrA[4][4], xrB[4][4];
            #pragma unroll
            for (int t = 0; t < 4; ++t)
                #pragma unroll
                for (int q = 0; q < 4; ++q) {
                    xrA[t][q] = fmaxf(fmaf(d2A[t][q], sm2[t], tm2[t]), 0.f);
                    xrB[t][q] = fmaxf(fmaf(d2B[t][q], sm2[t], tm2[t]), 0.f);
                }

            // X3: quad-channel b64 writes (pos 4r+t <-> ch 16t+r)
            #pragma unroll
            for (int q = 0; q < 4; ++q) {
                *(uint2*)&X3A[(4 * Q + q) * 72 + 4 * r] =
                    make_uint2(pk2(xrA[0][q], xrA[1][q]), pk2(xrA[2][q], xrA[3][q]));
                *(uint2*)&X3B[(4 * Q + q) * 72 + 4 * r] =
                    make_uint2(pk2(xrB[0][q], xrB[1][q]), pk2(xrB[2][q], xrB[3][q]));
            }
            const short8v a3lA = *(const short8v*)&X3A[r * 72 + Q * 8];
            const short8v a3hA = *(const short8v*)&X3A[r * 72 + 32 + Q * 8];
            const short8v a3lB = *(const short8v*)&X3B[r * 72 + Q * 8];
            const short8v a3hB = *(const short8v*)&X3B[r * 72 + 32 + Q * 8];

            // ---- interleaved ATT + softmax (scores prescaled by log2e) ----
            float seA[4], snA[4], seB[4], snB[4];
            #pragma unroll
            for (int t = 0; t < 4; ++t) {
                float4v sA = __builtin_amdgcn_mfma_f32_16x16x32_bf16(a3lA, b3f[t * 2],     z0, 0, 0, 0);
                sA         = __builtin_amdgcn_mfma_f32_16x16x32_bf16(a3hA, b3f[t * 2 + 1], sA, 0, 0, 0);
                float4v sB = __builtin_amdgcn_mfma_f32_16x16x32_bf16(a3lB, b3f[t * 2],     z0, 0, 0, 0);
                sB         = __builtin_amdgcn_mfma_f32_16x16x32_bf16(a3hB, b3f[t * 2 + 1], sB, 0, 0, 0);
                float e0A = fexp2(sA[0]), e1A = fexp2(sA[1]);
                float e2A = fexp2(sA[2]), e3A = fexp2(sA[3]);
                float e0B = fexp2(sB[0]), e1B = fexp2(sB[1]);
                float e2B = fexp2(sB[2]), e3B = fexp2(sB[3]);
                seA[t] = (e0A + e1A) + (e2A + e3A);
                snA[t] = fmaf(e0A, xrA[t][0], e1A * xrA[t][1]) + fmaf(e2A, xrA[t][2], e3A * xrA[t][3]);
                seB[t] = (e0B + e1B) + (e2B + e3B);
                snB[t] = fmaf(e0B, xrB[t][0], e1B * xrB[t][1]) + fmaf(e2B, xrB[t][2], e3B * xrB[t][3]);
            }
            #pragma unroll
            for (int t = 0; t < 4; ++t) {
                seA[t] += __shfl_xor(seA[t], 16, 64);
                snA[t] += __shfl_xor(snA[t], 16, 64);
                seB[t] += __shfl_xor(seB[t], 16, 64);
                snB[t] += __shfl_xor(snB[t], 16, 64);
                seA[t] += __shfl_xor(seA[t], 32, 64);
                snA[t] += __shfl_xor(snA[t], 32, 64);
                seB[t] += __shfl_xor(seB[t], 32, 64);
                snB[t] += __shfl_xor(snB[t], 32, 64);
            }
            // all-lane tail: lane handles t=Q, channel 16Q+r -> PL pos 4r+Q
            {
                const float snqA = (Q == 0) ? snA[0] : (Q == 1) ? snA[1] : (Q == 2) ? snA[2] : snA[3];
                const float seqA = (Q == 0) ? seA[0] : (Q == 1) ? seA[1] : (Q == 2) ? seA[2] : seA[3];
                const float snqB = (Q == 0) ? snB[0] : (Q == 1) ? snB[1] : (Q == 2) ? snB[2] : snB[3];
                const float seqB = (Q == 0) ? seB[0] : (Q == 1) ? seB[1] : (Q == 2) ? seB[2] : seB[3];
                sPL[(4 * it + 2 * pp) * 72 + 4 * r + Q]     = f2bf(__fdividef(snqA, seqA));
                sPL[(4 * it + 2 * pp + 1) * 72 + 4 * r + Q] = f2bf(__fdividef(snqB, seqB));
            }
        }
        __builtin_amdgcn_s_setprio(0);
    }

    // ===== ONE pool MFMA epilogue for all 16 block points (all lanes valid) =====
    short8v pbf[8];
    #pragma unroll
    for (int i = 0; i < 8; ++i) pbf[i] = FR[(14 + i) * 64 + l];
    float spv[4], tpv[4];
    #pragma unroll
    for (int t = 0; t < 4; ++t) {
        spv[t] = SC[(12 + t) * 64 + l]; tpv[t] = SC[(16 + t) * 64 + l];
    }
    const short8v apl0 = *(const short8v*)&sPL[r * 72 + Q * 8];
    const short8v apl1 = *(const short8v*)&sPL[r * 72 + 32 + Q * 8];
    float4v dp[4];
    #pragma unroll
    for (int t = 0; t < 4; ++t) {
        float4v d = __builtin_amdgcn_mfma_f32_16x16x32_bf16(apl0, pbf[t * 2],     z0, 0, 0, 0);
        d         = __builtin_amdgcn_mfma_f32_16x16x32_bf16(apl1, pbf[t * 2 + 1], d,  0, 0, 0);
        dp[t] = d;
    }
    // D: row = 4Q+q = block point, col = 16t+r = output channel -> dense stores
    #pragma unroll
    for (int q = 0; q < 4; ++q)
        #pragma unroll
        for (int t = 0; t < 4; ++t)
            out[(ptb + 4 * Q + q) * 64 + 16 * t + r] =
                fmaxf(fmaf(dp[t][q], spv[t], tpv[t]), 0.f);
}

extern "C" void kernel_launch(void* const* d_in, const int* in_sizes, int n_in,
                              void* d_out, int out_size, void* d_ws, size_t ws_size,
                              hipStream_t stream) {
    (void)in_sizes; (void)n_in; (void)ws_size; (void)out_size;
    const float* coords = (const float*)d_in[0];
    const float* feats  = (const float*)d_in[1];
    const int*   nidx   = (const int*)  d_in[2];
    const float* w1  = (const float*)d_in[3];
    const float* g1  = (const float*)d_in[4];
    const float* b1  = (const float*)d_in[5];
    const float* w2  = (const float*)d_in[6];
    const float* g2  = (const float*)d_in[7];
    const float* b2  = (const float*)d_in[8];
    const float* wm1 = (const float*)d_in[9];
    const float* gm1 = (const float*)d_in[10];
    const float* bm1 = (const float*)d_in[11];
    const float* wm2 = (const float*)d_in[12];
    const float* gm2 = (const float*)d_in[13];
    const float* bm2 = (const float*)d_in[14];
    const float* watt = (const float*)d_in[15];
    const float* wp  = (const float*)d_in[16];
    const float* gp  = (const float*)d_in[17];
    const float* bp  = (const float*)d_in[18];
    float* out = (float*)d_out;
    ushort* ws = (ushort*)d_ws;

    lfa_pack<<<dim3(12), dim3(256), 0, stream>>>(wm1, wm2, watt, wp,
                                                 gm1, bm1, gm2, bm2, gp, bp,
                                                 w2, g2, b2, ws);
    lfa_kernel<<<dim3(4096), dim3(64), 0, stream>>>(coords, feats, nidx,
                                                    w1, g1, b1, ws, out);
}